// Round 6
// baseline (394.909 us; speedup 1.0000x reference)
//
#include <hip/hip_runtime.h>
#include <cstddef>

#define D_FEAT 64
#define S_DIM 16
#define H_DIM 32
#define OUT_DIM 16
#define MAX_IT 5

typedef _Float16 half8 __attribute__((ext_vector_type(8)));

__device__ __forceinline__ float fast_tanh(float x) {
    float xc = fminf(fmaxf(x, -15.0f), 15.0f);
    float e = __expf(2.0f * xc);
    return (e - 1.0f) / (e + 1.0f);
}

// ---- CSR construction (counting sort by src) ----
__global__ __launch_bounds__(256)
void k_hist(const int* __restrict__ src, int* __restrict__ deg, int E) {
    int e = blockIdx.x * 256 + threadIdx.x;
    if (e < E) atomicAdd(&deg[src[e]], 1);
}

__global__ __launch_bounds__(1024)
void k_scan(const int* __restrict__ deg, int* __restrict__ cursor, int N) {
    __shared__ int wsum[16];
    __shared__ int carry;
    int lane = threadIdx.x & 63;
    int wid = threadIdx.x >> 6;
    if (threadIdx.x == 0) carry = 0;
    __syncthreads();
    for (int base = 0; base < N; base += 1024) {
        int i = base + (int)threadIdx.x;
        int v = (i < N) ? deg[i] : 0;
        int incl = v;
#pragma unroll
        for (int off = 1; off < 64; off <<= 1) {
            int t = __shfl_up(incl, off, 64);
            if (lane >= off) incl += t;
        }
        if (lane == 63) wsum[wid] = incl;
        __syncthreads();
        if (wid == 0) {
            int w = (lane < 16) ? wsum[lane] : 0;
            int wi = w;
#pragma unroll
            for (int off = 1; off < 16; off <<= 1) {
                int t = __shfl_up(wi, off, 64);
                if (lane >= off) wi += t;
            }
            if (lane < 16) wsum[lane] = wi - w;
        }
        __syncthreads();
        int excl = incl - v + wsum[wid] + carry;
        if (i < N) cursor[i] = excl;
        __syncthreads();
        if ((int)threadIdx.x == 1023) carry = excl + v;
        __syncthreads();
    }
}

__global__ __launch_bounds__(256)
void k_scatter(const int* __restrict__ src, const int* __restrict__ dst,
               int* __restrict__ cursor, int* __restrict__ pos,
               int* __restrict__ dstp, int* __restrict__ srcp, int E) {
    int e = blockIdx.x * 256 + threadIdx.x;
    if (e >= E) return;
    int s = src[e];
    int p = atomicAdd(&cursor[s], 1);
    pos[e] = p;
    dstp[p] = dst[e];
    srcp[p] = s;
}

// pre[pos[e]] = fp16(bst1 + feat[e] @ Wst1[:64]) — direct per-thread row reads
__global__ __launch_bounds__(256)
void k_pre(const float* __restrict__ feat, const float* __restrict__ Wst1,
           const float* __restrict__ bst1, const int* __restrict__ pos,
           _Float16* __restrict__ pre, int E) {
    int e = blockIdx.x * 256 + threadIdx.x;
    if (e >= E) return;
    float acc[H_DIM];
#pragma unroll
    for (int j = 0; j < H_DIM; ++j) acc[j] = bst1[j];
    const float4* f4 = reinterpret_cast<const float4*>(feat + (size_t)e * D_FEAT);
#pragma unroll 4
    for (int k4 = 0; k4 < D_FEAT / 4; ++k4) {
        float4 v = f4[k4];
        const float* w = Wst1 + k4 * 4 * H_DIM;
#pragma unroll
        for (int j = 0; j < H_DIM; ++j) acc[j] = fmaf(v.x, w[j], acc[j]);
#pragma unroll
        for (int j = 0; j < H_DIM; ++j) acc[j] = fmaf(v.y, w[H_DIM + j], acc[j]);
#pragma unroll
        for (int j = 0; j < H_DIM; ++j) acc[j] = fmaf(v.z, w[2 * H_DIM + j], acc[j]);
#pragma unroll
        for (int j = 0; j < H_DIM; ++j) acc[j] = fmaf(v.w, w[3 * H_DIM + j], acc[j]);
    }
    int p = pos[e];
    half8* op = reinterpret_cast<half8*>(pre + (size_t)p * H_DIM);
#pragma unroll
    for (int j8 = 0; j8 < 4; ++j8) {
        half8 v;
#pragma unroll
        for (int k = 0; k < 8; ++k) v[k] = (_Float16)acc[j8 * 8 + k];
        op[j8] = v;
    }
}

// Quad-per-edge fused edge MLP + parallel in-block segmented sum.
// Block = 1024 threads = 256 edges. All global loads coalesced:
//  - pre: wave reads 1KB contiguous (lane q of quad -> dims [8q,8q+8))
//  - nodeH: quad covers exactly one 128B row
// h[32] gathered via static-indexed __shfl; each lane computes only its 4 r-dims.
__global__ __launch_bounds__(1024)
void k_edge(const _Float16* __restrict__ pre, const float* __restrict__ nodeH,
            const int* __restrict__ dstp, const int* __restrict__ srcp,
            const float* __restrict__ Wst2, const float* __restrict__ bst2,
            float* __restrict__ new_state, const int* __restrict__ flags,
            int it, int E) {
#pragma unroll
    for (int j = 0; j < MAX_IT; ++j)
        if (j < it && flags[2 + j] == 0) return;  // converged earlier -> frozen
    __shared__ float sres[256][20];   // stride 20 dwords: b128-aligned rows
    __shared__ int ssrc[256];
    __shared__ int send_[256];
    __shared__ int segs[256];
    __shared__ int wf[4];
    __shared__ int nseg;
    const int t = threadIdx.x;
    const int base = blockIdx.x * 256;
    const int ei = t >> 2;            // edge slot within block
    const int q = t & 3;              // quad lane
    const int edge = base + ei;
    const bool valid = edge < E;
    if (t == 0) nseg = 0;
    if (t < 256) {
        int ee = base + t;
        ssrc[t] = (ee < E) ? srcp[ee] : (int)0x80000000;
    }

    if (valid) {
        int d = dstp[edge];
        half8 pv = *reinterpret_cast<const half8*>(pre + (size_t)edge * H_DIM + q * 8);
        const float4* hp = reinterpret_cast<const float4*>(nodeH + (size_t)d * H_DIM + q * 8);
        float4 a = hp[0], b = hp[1];
        float h8[8];
        h8[0] = fast_tanh((float)pv[0] + a.x);
        h8[1] = fast_tanh((float)pv[1] + a.y);
        h8[2] = fast_tanh((float)pv[2] + a.z);
        h8[3] = fast_tanh((float)pv[3] + a.w);
        h8[4] = fast_tanh((float)pv[4] + b.x);
        h8[5] = fast_tanh((float)pv[5] + b.y);
        h8[6] = fast_tanh((float)pv[6] + b.z);
        h8[7] = fast_tanh((float)pv[7] + b.w);

        // gather full h[32] from the quad (static payload index, per-j source lane)
        const int lq = (t & 63) & ~3;  // quad base lane within wave
        float h_all[H_DIM];
#pragma unroll
        for (int j = 0; j < H_DIM; ++j)
            h_all[j] = __shfl(h8[j & 7], lq + (j >> 3), 64);

        // r for this lane's 4 output dims: i in [4q, 4q+4)
        const float4* W4 = reinterpret_cast<const float4*>(Wst2);  // [32][4 float4]
        float4 bv = reinterpret_cast<const float4*>(bst2)[q];
        float r0 = bv.x, r1 = bv.y, r2 = bv.z, r3 = bv.w;
#pragma unroll
        for (int j = 0; j < H_DIM; ++j) {
            float hj = h_all[j];
            float4 w = W4[j * 4 + q];
            r0 = fmaf(hj, w.x, r0);
            r1 = fmaf(hj, w.y, r1);
            r2 = fmaf(hj, w.z, r2);
            r3 = fmaf(hj, w.w, r3);
        }
        float4 o = make_float4(fast_tanh(r0), fast_tanh(r1), fast_tanh(r2), fast_tanh(r3));
        *reinterpret_cast<float4*>(&sres[ei][4 * q]) = o;
    }
    __syncthreads();

    // ---- segment extents over the 256 edge slots (threads 0..255) ----
    int s = 0, mn = 0x7fffffff;
    bool head = false;
    if (t < 256) {
        s = ssrc[t];
        head = (t == 0) || (ssrc[t - 1] != s);
        bool tail = (t == 255) || (ssrc[t + 1] != s);
        mn = tail ? (t + 1) : 0x7fffffff;
        int lane = t & 63;
#pragma unroll
        for (int off = 1; off < 64; off <<= 1) {
            int u = __shfl_down(mn, off, 64);
            if (lane + off < 64) mn = min(mn, u);
        }
        if (lane == 0) wf[t >> 6] = mn;
    }
    __syncthreads();
    if (t < 256) {
        int wid = t >> 6;
        int carry = 0x7fffffff;
#pragma unroll
        for (int w = 0; w < 4; ++w)
            if (w > wid) carry = min(carry, wf[w]);
        send_[t] = min(mn, carry);
        int spos = -1;
        if (head && (base + t) < E) spos = atomicAdd(&nseg, 1);
        if (spos >= 0) segs[spos] = t;
    }
    __syncthreads();

    // ---- workers: one per (segment, dim) ----
    int ns = nseg;
    for (int w = t; w < ns * 16; w += 1024) {
        int st = segs[w >> 4];
        int dim = w & 15;
        int en = send_[st];
        int node = ssrc[st];
        float a = 0.f;
        for (int i = st; i < en; ++i) a += sres[i][dim];
        bool tS = (st > 0) || (base == 0) || (srcp[base - 1] != node);
        int gen = base + en;
        bool tE = (en < 256) || (gen >= E) || (srcp[gen] != node);
        float* p = new_state + (size_t)node * S_DIM + dim;
        if (tS && tE) *p = a;
        else atomicAdd(p, a);
    }
}

// 4 threads/node: convergence, state <- new_state, new_state <- 0, nodeH = state@Wst1[64:]
__global__ __launch_bounds__(256)
void k_node(float* __restrict__ state, float* __restrict__ new_state,
            float* __restrict__ nodeH, const float* __restrict__ Wst1,
            int* __restrict__ flags, int it, int N) {
#pragma unroll
    for (int j = 0; j < MAX_IT; ++j)
        if (j < it && flags[2 + j] == 0) return;
    int tt = blockIdx.x * 256 + threadIdx.x;
    int n = tt >> 2;
    int q = tt & 3;
    if (n >= N) return;
    float4* nsp = reinterpret_cast<float4*>(new_state + (size_t)n * S_DIM);
    float4* sp = reinterpret_cast<float4*>(state + (size_t)n * S_DIM);
    float4 acc = nsp[q];
    float4 old = sp[q];
    float dx = acc.x - old.x, dy = acc.y - old.y, dz = acc.z - old.z, dw = acc.w - old.w;
    float d2 = dx * dx + dy * dy + dz * dz + dw * dw;
    sp[q] = acc;
    nsp[q] = make_float4(0.f, 0.f, 0.f, 0.f);
    d2 += __shfl_xor(d2, 1);
    d2 += __shfl_xor(d2, 2);
    if (q == 0 && d2 + 1e-10f > 1e-4f) flags[2 + it] = 1;  // benign racy store of 1

    float st[S_DIM];
    st[q * 4 + 0] = acc.x; st[q * 4 + 1] = acc.y; st[q * 4 + 2] = acc.z; st[q * 4 + 3] = acc.w;
#pragma unroll
    for (int m = 1; m < 4; ++m) {
        int qs = q ^ m;
        st[qs * 4 + 0] = __shfl_xor(acc.x, m);
        st[qs * 4 + 1] = __shfl_xor(acc.y, m);
        st[qs * 4 + 2] = __shfl_xor(acc.z, m);
        st[qs * 4 + 3] = __shfl_xor(acc.w, m);
    }
    float hh[8];
#pragma unroll
    for (int j = 0; j < 8; ++j) hh[j] = 0.f;
#pragma unroll
    for (int k = 0; k < S_DIM; ++k) {
        const float* w = Wst1 + (size_t)(D_FEAT + k) * H_DIM + q * 8;
        float sk = st[k];
#pragma unroll
        for (int j = 0; j < 8; ++j) hh[j] = fmaf(sk, w[j], hh[j]);
    }
    float4* hp = reinterpret_cast<float4*>(nodeH + (size_t)n * H_DIM + q * 8);
    hp[0] = make_float4(hh[0], hh[1], hh[2], hh[3]);
    hp[1] = make_float4(hh[4], hh[5], hh[6], hh[7]);
}

__global__ __launch_bounds__(256)
void gnn_out(const float* __restrict__ state, const float* __restrict__ Wout1,
             const float* __restrict__ bout1, const float* __restrict__ Wout2,
             const float* __restrict__ bout2, float* __restrict__ out, int N) {
    int n = blockIdx.x * 256 + threadIdx.x;
    if (n >= N) return;
    float st[S_DIM];
    const float4* sp = reinterpret_cast<const float4*>(state + (size_t)n * S_DIM);
    float4 v0 = sp[0], v1 = sp[1], v2 = sp[2], v3 = sp[3];
    st[0] = v0.x; st[1] = v0.y; st[2] = v0.z; st[3] = v0.w;
    st[4] = v1.x; st[5] = v1.y; st[6] = v1.z; st[7] = v1.w;
    st[8] = v2.x; st[9] = v2.y; st[10] = v2.z; st[11] = v2.w;
    st[12] = v3.x; st[13] = v3.y; st[14] = v3.z; st[15] = v3.w;

    float h[H_DIM];
#pragma unroll
    for (int j = 0; j < H_DIM; ++j) {
        float acc = bout1[j];
#pragma unroll
        for (int k = 0; k < S_DIM; ++k) acc = fmaf(st[k], Wout1[(size_t)k * H_DIM + j], acc);
        h[j] = fast_tanh(acc);
    }
    float l[OUT_DIM];
#pragma unroll
    for (int i = 0; i < OUT_DIM; ++i) l[i] = bout2[i];
#pragma unroll
    for (int j = 0; j < H_DIM; ++j) {
        float hj = h[j];
#pragma unroll
        for (int i = 0; i < OUT_DIM; ++i) l[i] = fmaf(hj, Wout2[(size_t)j * OUT_DIM + i], l[i]);
    }
    float m = l[0];
#pragma unroll
    for (int i = 1; i < OUT_DIM; ++i) m = fmaxf(m, l[i]);
    float sum = 0.0f;
#pragma unroll
    for (int i = 0; i < OUT_DIM; ++i) {
        float tv = __expf(l[i] - m);
        l[i] = tv;
        sum += tv;
    }
    float inv = 1.0f / sum;
    float4* op = reinterpret_cast<float4*>(out + (size_t)n * OUT_DIM);
    op[0] = make_float4(l[0] * inv, l[1] * inv, l[2] * inv, l[3] * inv);
    op[1] = make_float4(l[4] * inv, l[5] * inv, l[6] * inv, l[7] * inv);
    op[2] = make_float4(l[8] * inv, l[9] * inv, l[10] * inv, l[11] * inv);
    op[3] = make_float4(l[12] * inv, l[13] * inv, l[14] * inv, l[15] * inv);
}

extern "C" void kernel_launch(void* const* d_in, const int* in_sizes, int n_in,
                              void* d_out, int out_size, void* d_ws, size_t ws_size,
                              hipStream_t stream) {
    const float* edge_feat = (const float*)d_in[0];
    const float* Wst1 = (const float*)d_in[1];
    const float* bst1 = (const float*)d_in[2];
    const float* Wst2 = (const float*)d_in[3];
    const float* bst2 = (const float*)d_in[4];
    const float* Wout1 = (const float*)d_in[5];
    const float* bout1 = (const float*)d_in[6];
    const float* Wout2 = (const float*)d_in[7];
    const float* bout2 = (const float*)d_in[8];
    const int* esrc = (const int*)d_in[9];
    const int* edst = (const int*)d_in[10];
    const int E = in_sizes[9];
    const int N = out_size / OUT_DIM;
    float* out = (float*)d_out;

    // ws layout (floats): state[N*16] | nodeH[N*32] | new_state[N*16] |
    // pre (_Float16, E*32) | pos[E] | dstp[E] | srcp[E] | deg[N] | cursor[N] | flags[8]
    float* state = (float*)d_ws;
    float* nodeH = state + (size_t)N * S_DIM;
    float* new_state = nodeH + (size_t)N * H_DIM;
    _Float16* pre = (_Float16*)(new_state + (size_t)N * S_DIM);
    int* pos = (int*)(pre + (size_t)E * H_DIM);
    int* dstp = pos + E;
    int* srcp = dstp + E;
    int* deg = srcp + E;
    int* cursor = deg + N;
    int* flags = cursor + N;

    hipMemsetAsync(state, 0, (size_t)N * (S_DIM + H_DIM + S_DIM) * sizeof(float), stream);
    hipMemsetAsync(deg, 0, (size_t)N * sizeof(int), stream);
    hipMemsetAsync(flags, 0, 8 * sizeof(int), stream);

    int ebl = (E + 255) / 256;
    int nbl = (N + 255) / 256;
    int rbl = (N * 4 + 255) / 256;

    k_hist<<<ebl, 256, 0, stream>>>(esrc, deg, E);
    k_scan<<<1, 1024, 0, stream>>>(deg, cursor, N);
    k_scatter<<<ebl, 256, 0, stream>>>(esrc, edst, cursor, pos, dstp, srcp, E);
    k_pre<<<ebl, 256, 0, stream>>>(edge_feat, Wst1, bst1, pos, pre, E);

    for (int it = 0; it < MAX_IT; ++it) {
        k_edge<<<ebl, 1024, 0, stream>>>(pre, nodeH, dstp, srcp, Wst2, bst2,
                                         new_state, flags, it, E);
        k_node<<<rbl, 256, 0, stream>>>(state, new_state, nodeH, Wst1, flags, it, N);
    }
    gnn_out<<<nbl, 256, 0, stream>>>(state, Wout1, bout1, Wout2, bout2, out, N);
}

// Round 7
// 327.346 us; speedup vs baseline: 1.2064x; 1.2064x over previous
//
#include <hip/hip_runtime.h>
#include <cstddef>

#define D_FEAT 64
#define S_DIM 16
#define H_DIM 32
#define OUT_DIM 16
#define MAX_IT 5

typedef _Float16 half8 __attribute__((ext_vector_type(8)));

__device__ __forceinline__ float fast_tanh(float x) {
    float xc = fminf(fmaxf(x, -15.0f), 15.0f);
    float e = __expf(2.0f * xc);
    return (e - 1.0f) / (e + 1.0f);
}

// ---- CSR construction (counting sort by src) ----
__global__ __launch_bounds__(256)
void k_hist(const int* __restrict__ src, int* __restrict__ deg, int E) {
    int e = blockIdx.x * 256 + threadIdx.x;
    if (e < E) atomicAdd(&deg[src[e]], 1);
}

__global__ __launch_bounds__(1024)
void k_scan(const int* __restrict__ deg, int* __restrict__ cursor, int N) {
    __shared__ int wsum[16];
    __shared__ int carry;
    int lane = threadIdx.x & 63;
    int wid = threadIdx.x >> 6;
    if (threadIdx.x == 0) carry = 0;
    __syncthreads();
    for (int base = 0; base < N; base += 1024) {
        int i = base + (int)threadIdx.x;
        int v = (i < N) ? deg[i] : 0;
        int incl = v;
#pragma unroll
        for (int off = 1; off < 64; off <<= 1) {
            int t = __shfl_up(incl, off, 64);
            if (lane >= off) incl += t;
        }
        if (lane == 63) wsum[wid] = incl;
        __syncthreads();
        if (wid == 0) {
            int w = (lane < 16) ? wsum[lane] : 0;
            int wi = w;
#pragma unroll
            for (int off = 1; off < 16; off <<= 1) {
                int t = __shfl_up(wi, off, 64);
                if (lane >= off) wi += t;
            }
            if (lane < 16) wsum[lane] = wi - w;
        }
        __syncthreads();
        int excl = incl - v + wsum[wid] + carry;
        if (i < N) cursor[i] = excl;
        __syncthreads();
        if ((int)threadIdx.x == 1023) carry = excl + v;
        __syncthreads();
    }
}

// iperm[p] = original edge index at sorted position p
__global__ __launch_bounds__(256)
void k_scatter(const int* __restrict__ src, const int* __restrict__ dst,
               int* __restrict__ cursor, int* __restrict__ iperm,
               int* __restrict__ dstp, int* __restrict__ srcp, int E) {
    int e = blockIdx.x * 256 + threadIdx.x;
    if (e >= E) return;
    int s = src[e];
    int p = atomicAdd(&cursor[s], 1);
    iperm[p] = e;
    dstp[p] = dst[e];
    srcp[p] = s;
}

// pre[e] = fp16(bst1 + feat[e] @ Wst1[:64]) — ORIGINAL order: read AND write stream
// sequentially (permutation moved to k_edge's 64B gather). unroll 8 -> 8 loads in flight.
__global__ __launch_bounds__(256)
void k_pre(const float* __restrict__ feat, const float* __restrict__ Wst1,
           const float* __restrict__ bst1, _Float16* __restrict__ pre, int E) {
    int e = blockIdx.x * 256 + threadIdx.x;
    if (e >= E) return;
    float acc[H_DIM];
#pragma unroll
    for (int j = 0; j < H_DIM; ++j) acc[j] = bst1[j];
    const float4* f4 = reinterpret_cast<const float4*>(feat + (size_t)e * D_FEAT);
#pragma unroll 8
    for (int k4 = 0; k4 < D_FEAT / 4; ++k4) {
        float4 v = f4[k4];
        const float* w = Wst1 + k4 * 4 * H_DIM;
#pragma unroll
        for (int j = 0; j < H_DIM; ++j) acc[j] = fmaf(v.x, w[j], acc[j]);
#pragma unroll
        for (int j = 0; j < H_DIM; ++j) acc[j] = fmaf(v.y, w[H_DIM + j], acc[j]);
#pragma unroll
        for (int j = 0; j < H_DIM; ++j) acc[j] = fmaf(v.z, w[2 * H_DIM + j], acc[j]);
#pragma unroll
        for (int j = 0; j < H_DIM; ++j) acc[j] = fmaf(v.w, w[3 * H_DIM + j], acc[j]);
    }
    half8* op = reinterpret_cast<half8*>(pre + (size_t)e * H_DIM);
#pragma unroll
    for (int j8 = 0; j8 < 4; ++j8) {
        half8 v;
#pragma unroll
        for (int k = 0; k < 8; ++k) v[k] = (_Float16)acc[j8 * 8 + k];
        op[j8] = v;
    }
}

// Fused: edge MLP + PARALLEL in-block segmented sum -> new_state (round-5 structure).
// pre gathered via iperm (64B row = 1 line, L3-resident); all loads issued up-front.
__global__ __launch_bounds__(256)
void k_edge(const _Float16* __restrict__ pre, const float* __restrict__ nodeH,
            const int* __restrict__ iperm, const int* __restrict__ dstp,
            const int* __restrict__ srcp, const float* __restrict__ Wst2,
            const float* __restrict__ bst2, float* __restrict__ new_state,
            const int* __restrict__ flags, int it, int E) {
#pragma unroll
    for (int j = 0; j < MAX_IT; ++j)
        if (j < it && flags[2 + j] == 0) return;  // converged earlier -> frozen
    __shared__ float sres[256][17];
    __shared__ int ssrc[256];
    __shared__ int send_[256];
    __shared__ int segs[256];
    __shared__ int wf[4];
    __shared__ int nseg;
    const int t = threadIdx.x;
    const int lane = t & 63;
    const int wid = t >> 6;
    const int base = blockIdx.x * 256;
    const int ep = base + t;
    const bool valid = ep < E;
    if (t == 0) nseg = 0;

    int s = valid ? srcp[ep] : (int)0x80000000;
    ssrc[t] = s;

    if (valid) {
        int eo = iperm[ep];
        int d = dstp[ep];
        // issue ALL loads before compute (pre: one 64B row; nodeH: one 128B row)
        const half8* pp = reinterpret_cast<const half8*>(pre + (size_t)eo * H_DIM);
        const float4* hp = reinterpret_cast<const float4*>(nodeH + (size_t)d * H_DIM);
        half8 p0 = pp[0], p1 = pp[1], p2 = pp[2], p3 = pp[3];
        float4 a0 = hp[0], a1 = hp[1], a2 = hp[2], a3 = hp[3];
        float4 a4 = hp[4], a5 = hp[5], a6 = hp[6], a7 = hp[7];

        float h[H_DIM];
        h[0]  = fast_tanh((float)p0[0] + a0.x);
        h[1]  = fast_tanh((float)p0[1] + a0.y);
        h[2]  = fast_tanh((float)p0[2] + a0.z);
        h[3]  = fast_tanh((float)p0[3] + a0.w);
        h[4]  = fast_tanh((float)p0[4] + a1.x);
        h[5]  = fast_tanh((float)p0[5] + a1.y);
        h[6]  = fast_tanh((float)p0[6] + a1.z);
        h[7]  = fast_tanh((float)p0[7] + a1.w);
        h[8]  = fast_tanh((float)p1[0] + a2.x);
        h[9]  = fast_tanh((float)p1[1] + a2.y);
        h[10] = fast_tanh((float)p1[2] + a2.z);
        h[11] = fast_tanh((float)p1[3] + a2.w);
        h[12] = fast_tanh((float)p1[4] + a3.x);
        h[13] = fast_tanh((float)p1[5] + a3.y);
        h[14] = fast_tanh((float)p1[6] + a3.z);
        h[15] = fast_tanh((float)p1[7] + a3.w);
        h[16] = fast_tanh((float)p2[0] + a4.x);
        h[17] = fast_tanh((float)p2[1] + a4.y);
        h[18] = fast_tanh((float)p2[2] + a4.z);
        h[19] = fast_tanh((float)p2[3] + a4.w);
        h[20] = fast_tanh((float)p2[4] + a5.x);
        h[21] = fast_tanh((float)p2[5] + a5.y);
        h[22] = fast_tanh((float)p2[6] + a5.z);
        h[23] = fast_tanh((float)p2[7] + a5.w);
        h[24] = fast_tanh((float)p3[0] + a6.x);
        h[25] = fast_tanh((float)p3[1] + a6.y);
        h[26] = fast_tanh((float)p3[2] + a6.z);
        h[27] = fast_tanh((float)p3[3] + a6.w);
        h[28] = fast_tanh((float)p3[4] + a7.x);
        h[29] = fast_tanh((float)p3[5] + a7.y);
        h[30] = fast_tanh((float)p3[6] + a7.z);
        h[31] = fast_tanh((float)p3[7] + a7.w);

        float r[S_DIM];
#pragma unroll
        for (int i = 0; i < S_DIM; ++i) r[i] = bst2[i];
#pragma unroll
        for (int j = 0; j < H_DIM; ++j) {
            const float* w = Wst2 + (size_t)j * S_DIM;  // wave-uniform -> s_load
            float hj = h[j];
#pragma unroll
            for (int i = 0; i < S_DIM; ++i) r[i] = fmaf(hj, w[i], r[i]);
        }
#pragma unroll
        for (int i = 0; i < S_DIM; ++i) sres[t][i] = fast_tanh(r[i]);
    }
    __syncthreads();

    // segment heads/tails from sorted src
    bool head = (t == 0) || (ssrc[t - 1] != s);
    bool tail = (t == 255) || (ssrc[t + 1] != s);

    // per-wave inclusive min-scan (from the right) of tail positions -> segment end
    int mn = tail ? (t + 1) : 0x7fffffff;
#pragma unroll
    for (int off = 1; off < 64; off <<= 1) {
        int u = __shfl_down(mn, off, 64);
        if (lane + off < 64) mn = min(mn, u);
    }
    if (lane == 0) wf[wid] = mn;
    __syncthreads();
    int carry = 0x7fffffff;
#pragma unroll
    for (int w = 0; w < 4; ++w)
        if (w > wid) carry = min(carry, wf[w]);
    send_[t] = min(mn, carry);
    int spos = -1;
    if (head && valid) spos = atomicAdd(&nseg, 1);
    if (spos >= 0) segs[spos] = t;
    __syncthreads();

    // workers: one per (segment, dim)
    int ns = nseg;
    for (int w = t; w < ns * 16; w += 256) {
        int st = segs[w >> 4];
        int dim = w & 15;
        int en = send_[st];
        int node = ssrc[st];
        float a = 0.f;
        for (int i = st; i < en; ++i) a += sres[i][dim];
        bool tS = (st > 0) || (base == 0) || (srcp[base - 1] != node);
        int gen = base + en;
        bool tE = (en < 256) || (gen >= E) || (srcp[gen] != node);
        float* p = new_state + (size_t)node * S_DIM + dim;
        if (tS && tE) *p = a;
        else atomicAdd(p, a);
    }
}

// 4 threads/node: convergence, state <- new_state, new_state <- 0, nodeH = state@Wst1[64:]
__global__ __launch_bounds__(256)
void k_node(float* __restrict__ state, float* __restrict__ new_state,
            float* __restrict__ nodeH, const float* __restrict__ Wst1,
            int* __restrict__ flags, int it, int N) {
#pragma unroll
    for (int j = 0; j < MAX_IT; ++j)
        if (j < it && flags[2 + j] == 0) return;
    int tt = blockIdx.x * 256 + threadIdx.x;
    int n = tt >> 2;
    int q = tt & 3;
    if (n >= N) return;
    float4* nsp = reinterpret_cast<float4*>(new_state + (size_t)n * S_DIM);
    float4* sp = reinterpret_cast<float4*>(state + (size_t)n * S_DIM);
    float4 acc = nsp[q];
    float4 old = sp[q];
    float dx = acc.x - old.x, dy = acc.y - old.y, dz = acc.z - old.z, dw = acc.w - old.w;
    float d2 = dx * dx + dy * dy + dz * dz + dw * dw;
    sp[q] = acc;
    nsp[q] = make_float4(0.f, 0.f, 0.f, 0.f);
    d2 += __shfl_xor(d2, 1);
    d2 += __shfl_xor(d2, 2);
    if (q == 0 && d2 + 1e-10f > 1e-4f) flags[2 + it] = 1;  // benign racy store of 1

    float st[S_DIM];
    st[q * 4 + 0] = acc.x; st[q * 4 + 1] = acc.y; st[q * 4 + 2] = acc.z; st[q * 4 + 3] = acc.w;
#pragma unroll
    for (int m = 1; m < 4; ++m) {
        int qs = q ^ m;
        st[qs * 4 + 0] = __shfl_xor(acc.x, m);
        st[qs * 4 + 1] = __shfl_xor(acc.y, m);
        st[qs * 4 + 2] = __shfl_xor(acc.z, m);
        st[qs * 4 + 3] = __shfl_xor(acc.w, m);
    }
    float hh[8];
#pragma unroll
    for (int j = 0; j < 8; ++j) hh[j] = 0.f;
#pragma unroll
    for (int k = 0; k < S_DIM; ++k) {
        const float* w = Wst1 + (size_t)(D_FEAT + k) * H_DIM + q * 8;
        float sk = st[k];
#pragma unroll
        for (int j = 0; j < 8; ++j) hh[j] = fmaf(sk, w[j], hh[j]);
    }
    float4* hp = reinterpret_cast<float4*>(nodeH + (size_t)n * H_DIM + q * 8);
    hp[0] = make_float4(hh[0], hh[1], hh[2], hh[3]);
    hp[1] = make_float4(hh[4], hh[5], hh[6], hh[7]);
}

__global__ __launch_bounds__(256)
void gnn_out(const float* __restrict__ state, const float* __restrict__ Wout1,
             const float* __restrict__ bout1, const float* __restrict__ Wout2,
             const float* __restrict__ bout2, float* __restrict__ out, int N) {
    int n = blockIdx.x * 256 + threadIdx.x;
    if (n >= N) return;
    float st[S_DIM];
    const float4* sp = reinterpret_cast<const float4*>(state + (size_t)n * S_DIM);
    float4 v0 = sp[0], v1 = sp[1], v2 = sp[2], v3 = sp[3];
    st[0] = v0.x; st[1] = v0.y; st[2] = v0.z; st[3] = v0.w;
    st[4] = v1.x; st[5] = v1.y; st[6] = v1.z; st[7] = v1.w;
    st[8] = v2.x; st[9] = v2.y; st[10] = v2.z; st[11] = v2.w;
    st[12] = v3.x; st[13] = v3.y; st[14] = v3.z; st[15] = v3.w;

    float h[H_DIM];
#pragma unroll
    for (int j = 0; j < H_DIM; ++j) {
        float acc = bout1[j];
#pragma unroll
        for (int k = 0; k < S_DIM; ++k) acc = fmaf(st[k], Wout1[(size_t)k * H_DIM + j], acc);
        h[j] = fast_tanh(acc);
    }
    float l[OUT_DIM];
#pragma unroll
    for (int i = 0; i < OUT_DIM; ++i) l[i] = bout2[i];
#pragma unroll
    for (int j = 0; j < H_DIM; ++j) {
        float hj = h[j];
#pragma unroll
        for (int i = 0; i < OUT_DIM; ++i) l[i] = fmaf(hj, Wout2[(size_t)j * OUT_DIM + i], l[i]);
    }
    float m = l[0];
#pragma unroll
    for (int i = 1; i < OUT_DIM; ++i) m = fmaxf(m, l[i]);
    float sum = 0.0f;
#pragma unroll
    for (int i = 0; i < OUT_DIM; ++i) {
        float tv = __expf(l[i] - m);
        l[i] = tv;
        sum += tv;
    }
    float inv = 1.0f / sum;
    float4* op = reinterpret_cast<float4*>(out + (size_t)n * OUT_DIM);
    op[0] = make_float4(l[0] * inv, l[1] * inv, l[2] * inv, l[3] * inv);
    op[1] = make_float4(l[4] * inv, l[5] * inv, l[6] * inv, l[7] * inv);
    op[2] = make_float4(l[8] * inv, l[9] * inv, l[10] * inv, l[11] * inv);
    op[3] = make_float4(l[12] * inv, l[13] * inv, l[14] * inv, l[15] * inv);
}

extern "C" void kernel_launch(void* const* d_in, const int* in_sizes, int n_in,
                              void* d_out, int out_size, void* d_ws, size_t ws_size,
                              hipStream_t stream) {
    const float* edge_feat = (const float*)d_in[0];
    const float* Wst1 = (const float*)d_in[1];
    const float* bst1 = (const float*)d_in[2];
    const float* Wst2 = (const float*)d_in[3];
    const float* bst2 = (const float*)d_in[4];
    const float* Wout1 = (const float*)d_in[5];
    const float* bout1 = (const float*)d_in[6];
    const float* Wout2 = (const float*)d_in[7];
    const float* bout2 = (const float*)d_in[8];
    const int* esrc = (const int*)d_in[9];
    const int* edst = (const int*)d_in[10];
    const int E = in_sizes[9];
    const int N = out_size / OUT_DIM;
    float* out = (float*)d_out;

    // ws layout (floats): state[N*16] | nodeH[N*32] | new_state[N*16] |
    // pre (_Float16, E*32) | iperm[E] | dstp[E] | srcp[E] | deg[N] | cursor[N] | flags[8]
    float* state = (float*)d_ws;
    float* nodeH = state + (size_t)N * S_DIM;
    float* new_state = nodeH + (size_t)N * H_DIM;
    _Float16* pre = (_Float16*)(new_state + (size_t)N * S_DIM);
    int* iperm = (int*)(pre + (size_t)E * H_DIM);
    int* dstp = iperm + E;
    int* srcp = dstp + E;
    int* deg = srcp + E;
    int* cursor = deg + N;
    int* flags = cursor + N;

    hipMemsetAsync(state, 0, (size_t)N * (S_DIM + H_DIM + S_DIM) * sizeof(float), stream);
    hipMemsetAsync(deg, 0, (size_t)N * sizeof(int), stream);
    hipMemsetAsync(flags, 0, 8 * sizeof(int), stream);

    int ebl = (E + 255) / 256;
    int nbl = (N + 255) / 256;
    int rbl = (N * 4 + 255) / 256;

    k_hist<<<ebl, 256, 0, stream>>>(esrc, deg, E);
    k_scan<<<1, 1024, 0, stream>>>(deg, cursor, N);
    k_scatter<<<ebl, 256, 0, stream>>>(esrc, edst, cursor, iperm, dstp, srcp, E);
    k_pre<<<ebl, 256, 0, stream>>>(edge_feat, Wst1, bst1, pre, E);

    for (int it = 0; it < MAX_IT; ++it) {
        k_edge<<<ebl, 256, 0, stream>>>(pre, nodeH, iperm, dstp, srcp, Wst2, bst2,
                                        new_state, flags, it, E);
        k_node<<<rbl, 256, 0, stream>>>(state, new_state, nodeH, Wst1, flags, it, N);
    }
    gnn_out<<<nbl, 256, 0, stream>>>(state, Wout1, bout1, Wout2, bout2, out, N);
}

// Round 9
// 287.407 us; speedup vs baseline: 1.3740x; 1.1390x over previous
//
#include <hip/hip_runtime.h>
#include <cstddef>

#define D_FEAT 64
#define S_DIM 16
#define H_DIM 32
#define OUT_DIM 16
#define MAX_IT 5

typedef _Float16 half8 __attribute__((ext_vector_type(8)));

__device__ __forceinline__ float fast_tanh(float x) {
    float xc = fminf(fmaxf(x, -15.0f), 15.0f);
    float e = __expf(2.0f * xc);
    return (e - 1.0f) / (e + 1.0f);
}

// ---- CSR construction (counting sort by src) ----
__global__ __launch_bounds__(256)
void k_hist(const int* __restrict__ src, int* __restrict__ deg, int E) {
    int e = blockIdx.x * 256 + threadIdx.x;
    if (e < E) atomicAdd(&deg[src[e]], 1);
}

__global__ __launch_bounds__(1024)
void k_scan(const int* __restrict__ deg, int* __restrict__ cursor, int N) {
    __shared__ int wsum[16];
    __shared__ int carry;
    int lane = threadIdx.x & 63;
    int wid = threadIdx.x >> 6;
    if (threadIdx.x == 0) carry = 0;
    __syncthreads();
    for (int base = 0; base < N; base += 1024) {
        int i = base + (int)threadIdx.x;
        int v = (i < N) ? deg[i] : 0;
        int incl = v;
#pragma unroll
        for (int off = 1; off < 64; off <<= 1) {
            int t = __shfl_up(incl, off, 64);
            if (lane >= off) incl += t;
        }
        if (lane == 63) wsum[wid] = incl;
        __syncthreads();
        if (wid == 0) {
            int w = (lane < 16) ? wsum[lane] : 0;
            int wi = w;
#pragma unroll
            for (int off = 1; off < 16; off <<= 1) {
                int t = __shfl_up(wi, off, 64);
                if (lane >= off) wi += t;
            }
            if (lane < 16) wsum[lane] = wi - w;
        }
        __syncthreads();
        int excl = incl - v + wsum[wid] + carry;
        if (i < N) cursor[i] = excl;
        __syncthreads();
        if ((int)threadIdx.x == 1023) carry = excl + v;
        __syncthreads();
    }
}

// pos[e] = sorted position; dstp/srcp in sorted order.
// After this kernel, cursor[n] = END of node n's run (rowptr[n+1]).
__global__ __launch_bounds__(256)
void k_scatter(const int* __restrict__ src, const int* __restrict__ dst,
               int* __restrict__ cursor, int* __restrict__ pos,
               int* __restrict__ dstp, int* __restrict__ srcp, int E) {
    int e = blockIdx.x * 256 + threadIdx.x;
    if (e >= E) return;
    int s = src[e];
    int p = atomicAdd(&cursor[s], 1);
    pos[e] = p;
    dstp[p] = dst[e];
    srcp[p] = s;
}

// pre[pos[e]] = fp16(bst1 + feat[e] @ Wst1[:64]) — coalesced read, scattered 64B write
__global__ __launch_bounds__(256)
void k_pre(const float* __restrict__ feat, const float* __restrict__ Wst1,
           const float* __restrict__ bst1, const int* __restrict__ pos,
           _Float16* __restrict__ pre, int E) {
    int e = blockIdx.x * 256 + threadIdx.x;
    if (e >= E) return;
    float acc[H_DIM];
#pragma unroll
    for (int j = 0; j < H_DIM; ++j) acc[j] = bst1[j];
    const float4* f4 = reinterpret_cast<const float4*>(feat + (size_t)e * D_FEAT);
#pragma unroll 8
    for (int k4 = 0; k4 < D_FEAT / 4; ++k4) {
        float4 v = f4[k4];
        const float* w = Wst1 + k4 * 4 * H_DIM;
#pragma unroll
        for (int j = 0; j < H_DIM; ++j) acc[j] = fmaf(v.x, w[j], acc[j]);
#pragma unroll
        for (int j = 0; j < H_DIM; ++j) acc[j] = fmaf(v.y, w[H_DIM + j], acc[j]);
#pragma unroll
        for (int j = 0; j < H_DIM; ++j) acc[j] = fmaf(v.z, w[2 * H_DIM + j], acc[j]);
#pragma unroll
        for (int j = 0; j < H_DIM; ++j) acc[j] = fmaf(v.w, w[3 * H_DIM + j], acc[j]);
    }
    int p = pos[e];
    half8* op = reinterpret_cast<half8*>(pre + (size_t)p * H_DIM);
#pragma unroll
    for (int j8 = 0; j8 < 4; ++j8) {
        half8 v;
#pragma unroll
        for (int k = 0; k < 8; ++k) v[k] = (_Float16)acc[j8 * 8 + k];
        op[j8] = v;
    }
}

// Fused: edge MLP + parallel in-block segmented sum -> new_state.
// Segment ends come from rowend[] (post-scatter cursor) — no per-iteration scan.
// nodeH is fp16 (64B row): halves the random-gather line count.
__global__ __launch_bounds__(256)
void k_edge(const _Float16* __restrict__ pre, const _Float16* __restrict__ nodeH16,
            const int* __restrict__ dstp, const int* __restrict__ srcp,
            const int* __restrict__ rowend, const float* __restrict__ Wst2,
            const float* __restrict__ bst2, float* __restrict__ new_state,
            const int* __restrict__ flags, int it, int E) {
#pragma unroll
    for (int j = 0; j < MAX_IT; ++j)
        if (j < it && flags[2 + j] == 0) return;  // converged earlier -> frozen
    __shared__ float sres[256][17];
    __shared__ int ssrc[256];
    __shared__ int segnode[256];
    __shared__ int segstart[256];
    __shared__ int segend[256];
    __shared__ int segflag[256];
    __shared__ int nseg;
    const int t = threadIdx.x;
    const int base = blockIdx.x * 256;
    const int ep = base + t;
    const bool valid = ep < E;
    if (t == 0) nseg = 0;

    int s = valid ? srcp[ep] : (int)0x80000000;
    ssrc[t] = s;

    if (valid) {
        const half8* pp = reinterpret_cast<const half8*>(pre + (size_t)ep * H_DIM);
        half8 p0 = pp[0], p1 = pp[1], p2 = pp[2], p3 = pp[3];
        float h[H_DIM];
        if (it == 0) {  // state0 = 0 -> nodeH = 0
#pragma unroll
            for (int k = 0; k < 8; ++k) {
                h[k]      = fast_tanh((float)p0[k]);
                h[8 + k]  = fast_tanh((float)p1[k]);
                h[16 + k] = fast_tanh((float)p2[k]);
                h[24 + k] = fast_tanh((float)p3[k]);
            }
        } else {
            int d = dstp[ep];
            const half8* np = reinterpret_cast<const half8*>(nodeH16 + (size_t)d * H_DIM);
            half8 n0 = np[0], n1 = np[1], n2 = np[2], n3 = np[3];
#pragma unroll
            for (int k = 0; k < 8; ++k) {
                h[k]      = fast_tanh((float)p0[k] + (float)n0[k]);
                h[8 + k]  = fast_tanh((float)p1[k] + (float)n1[k]);
                h[16 + k] = fast_tanh((float)p2[k] + (float)n2[k]);
                h[24 + k] = fast_tanh((float)p3[k] + (float)n3[k]);
            }
        }
        float r[S_DIM];
#pragma unroll
        for (int i = 0; i < S_DIM; ++i) r[i] = bst2[i];
#pragma unroll
        for (int j = 0; j < H_DIM; ++j) {
            const float* w = Wst2 + (size_t)j * S_DIM;  // wave-uniform -> s_load
            float hj = h[j];
#pragma unroll
            for (int i = 0; i < S_DIM; ++i) r[i] = fmaf(hj, w[i], r[i]);
        }
#pragma unroll
        for (int i = 0; i < S_DIM; ++i) sres[t][i] = fast_tanh(r[i]);
    }
    __syncthreads();

    // segment heads register themselves; end comes from rowend (1 global 4B load)
    bool head = valid && ((t == 0) || (ssrc[t - 1] != s));
    if (head) {
        int slot = atomicAdd(&nseg, 1);
        int re = rowend[s];                       // global end of node s's run
        int en = re - base; if (en > 256) en = 256;
        bool tS = (t > 0) || (ep == 0) || (srcp[ep - 1] != s);
        bool tE = (re <= base + 256);
        segnode[slot] = s;
        segstart[slot] = t;
        segend[slot] = en;
        segflag[slot] = (tS && tE) ? 1 : 0;
    }
    __syncthreads();

    // workers: one per (segment, dim)
    int ns = nseg;
    for (int w = t; w < ns * 16; w += 256) {
        int slot = w >> 4;
        int dim = w & 15;
        int st = segstart[slot];
        int en = segend[slot];
        int node = segnode[slot];
        float a = 0.f;
        for (int i = st; i < en; ++i) a += sres[i][dim];
        float* p = new_state + (size_t)node * S_DIM + dim;
        if (segflag[slot]) *p = a;
        else atomicAdd(p, a);
    }
}

// 4 threads/node: convergence, state <- new_state, new_state <- 0, nodeH16 = fp16(state@Wst1[64:])
__global__ __launch_bounds__(256)
void k_node(float* __restrict__ state, float* __restrict__ new_state,
            _Float16* __restrict__ nodeH16, const float* __restrict__ Wst1,
            int* __restrict__ flags, int it, int N) {
#pragma unroll
    for (int j = 0; j < MAX_IT; ++j)
        if (j < it && flags[2 + j] == 0) return;
    int tt = blockIdx.x * 256 + threadIdx.x;
    int n = tt >> 2;
    int q = tt & 3;
    if (n >= N) return;
    float4* nsp = reinterpret_cast<float4*>(new_state + (size_t)n * S_DIM);
    float4* sp = reinterpret_cast<float4*>(state + (size_t)n * S_DIM);
    float4 acc = nsp[q];
    float4 old = sp[q];
    float dx = acc.x - old.x, dy = acc.y - old.y, dz = acc.z - old.z, dw = acc.w - old.w;
    float d2 = dx * dx + dy * dy + dz * dz + dw * dw;
    sp[q] = acc;
    nsp[q] = make_float4(0.f, 0.f, 0.f, 0.f);
    d2 += __shfl_xor(d2, 1);
    d2 += __shfl_xor(d2, 2);
    if (q == 0 && d2 + 1e-10f > 1e-4f) flags[2 + it] = 1;  // benign racy store

    float st[S_DIM];
    st[q * 4 + 0] = acc.x; st[q * 4 + 1] = acc.y; st[q * 4 + 2] = acc.z; st[q * 4 + 3] = acc.w;
#pragma unroll
    for (int m = 1; m < 4; ++m) {
        int qs = q ^ m;
        st[qs * 4 + 0] = __shfl_xor(acc.x, m);
        st[qs * 4 + 1] = __shfl_xor(acc.y, m);
        st[qs * 4 + 2] = __shfl_xor(acc.z, m);
        st[qs * 4 + 3] = __shfl_xor(acc.w, m);
    }
    float hh[8];
#pragma unroll
    for (int j = 0; j < 8; ++j) hh[j] = 0.f;
#pragma unroll
    for (int k = 0; k < S_DIM; ++k) {
        const float* w = Wst1 + (size_t)(D_FEAT + k) * H_DIM + q * 8;
        float sk = st[k];
#pragma unroll
        for (int j = 0; j < 8; ++j) hh[j] = fmaf(sk, w[j], hh[j]);
    }
    half8 hv;
#pragma unroll
    for (int j = 0; j < 8; ++j) hv[j] = (_Float16)hh[j];
    *reinterpret_cast<half8*>(nodeH16 + (size_t)n * H_DIM + q * 8) = hv;
}

__global__ __launch_bounds__(256)
void gnn_out(const float* __restrict__ state, const float* __restrict__ Wout1,
             const float* __restrict__ bout1, const float* __restrict__ Wout2,
             const float* __restrict__ bout2, float* __restrict__ out, int N) {
    int n = blockIdx.x * 256 + threadIdx.x;
    if (n >= N) return;
    float st[S_DIM];
    const float4* sp = reinterpret_cast<const float4*>(state + (size_t)n * S_DIM);
    float4 v0 = sp[0], v1 = sp[1], v2 = sp[2], v3 = sp[3];
    st[0] = v0.x; st[1] = v0.y; st[2] = v0.z; st[3] = v0.w;
    st[4] = v1.x; st[5] = v1.y; st[6] = v1.z; st[7] = v1.w;
    st[8] = v2.x; st[9] = v2.y; st[10] = v2.z; st[11] = v2.w;
    st[12] = v3.x; st[13] = v3.y; st[14] = v3.z; st[15] = v3.w;

    float h[H_DIM];
#pragma unroll
    for (int j = 0; j < H_DIM; ++j) {
        float acc = bout1[j];
#pragma unroll
        for (int k = 0; k < S_DIM; ++k) acc = fmaf(st[k], Wout1[(size_t)k * H_DIM + j], acc);
        h[j] = fast_tanh(acc);
    }
    float l[OUT_DIM];
#pragma unroll
    for (int i = 0; i < OUT_DIM; ++i) l[i] = bout2[i];
#pragma unroll
    for (int j = 0; j < H_DIM; ++j) {
        float hj = h[j];
#pragma unroll
        for (int i = 0; i < OUT_DIM; ++i) l[i] = fmaf(hj, Wout2[(size_t)j * OUT_DIM + i], l[i]);
    }
    float m = l[0];
#pragma unroll
    for (int i = 1; i < OUT_DIM; ++i) m = fmaxf(m, l[i]);
    float sum = 0.0f;
#pragma unroll
    for (int i = 0; i < OUT_DIM; ++i) {
        float tv = __expf(l[i] - m);
        l[i] = tv;
        sum += tv;
    }
    float inv = 1.0f / sum;
    float4* op = reinterpret_cast<float4*>(out + (size_t)n * OUT_DIM);
    op[0] = make_float4(l[0] * inv, l[1] * inv, l[2] * inv, l[3] * inv);
    op[1] = make_float4(l[4] * inv, l[5] * inv, l[6] * inv, l[7] * inv);
    op[2] = make_float4(l[8] * inv, l[9] * inv, l[10] * inv, l[11] * inv);
    op[3] = make_float4(l[12] * inv, l[13] * inv, l[14] * inv, l[15] * inv);
}

extern "C" void kernel_launch(void* const* d_in, const int* in_sizes, int n_in,
                              void* d_out, int out_size, void* d_ws, size_t ws_size,
                              hipStream_t stream) {
    const float* edge_feat = (const float*)d_in[0];
    const float* Wst1 = (const float*)d_in[1];
    const float* bst1 = (const float*)d_in[2];
    const float* Wst2 = (const float*)d_in[3];
    const float* bst2 = (const float*)d_in[4];
    const float* Wout1 = (const float*)d_in[5];
    const float* bout1 = (const float*)d_in[6];
    const float* Wout2 = (const float*)d_in[7];
    const float* bout2 = (const float*)d_in[8];
    const int* esrc = (const int*)d_in[9];
    const int* edst = (const int*)d_in[10];
    const int E = in_sizes[9];
    const int N = out_size / OUT_DIM;
    float* out = (float*)d_out;

    // ws layout (floats): state[N*16] | new_state[N*16] | pre (_Float16, E*32) |
    // nodeH16 (_Float16, N*32) | pos[E] | dstp[E] | srcp[E] | deg[N] | cursor[N] | flags[8]
    float* state = (float*)d_ws;
    float* new_state = state + (size_t)N * S_DIM;
    _Float16* pre = (_Float16*)(new_state + (size_t)N * S_DIM);
    _Float16* nodeH16 = pre + (size_t)E * H_DIM;
    int* pos = (int*)(nodeH16 + (size_t)N * H_DIM);
    int* dstp = pos + E;
    int* srcp = dstp + E;
    int* deg = srcp + E;
    int* cursor = deg + N;
    int* flags = cursor + N;

    hipMemsetAsync(state, 0, (size_t)N * S_DIM * 2 * sizeof(float), stream);
    hipMemsetAsync(deg, 0, (size_t)N * sizeof(int), stream);
    hipMemsetAsync(flags, 0, 8 * sizeof(int), stream);

    int ebl = (E + 255) / 256;
    int nbl = (N + 255) / 256;
    int rbl = (N * 4 + 255) / 256;

    k_hist<<<ebl, 256, 0, stream>>>(esrc, deg, E);
    k_scan<<<1, 1024, 0, stream>>>(deg, cursor, N);
    k_scatter<<<ebl, 256, 0, stream>>>(esrc, edst, cursor, pos, dstp, srcp, E);
    k_pre<<<ebl, 256, 0, stream>>>(edge_feat, Wst1, bst1, pos, pre, E);

    for (int it = 0; it < MAX_IT; ++it) {
        k_edge<<<ebl, 256, 0, stream>>>(pre, nodeH16, dstp, srcp, cursor, Wst2, bst2,
                                        new_state, flags, it, E);
        k_node<<<rbl, 256, 0, stream>>>(state, new_state, nodeH16, Wst1, flags, it, N);
    }
    gnn_out<<<nbl, 256, 0, stream>>>(state, Wout1, bout1, Wout2, bout2, out, N);
}